// Round 1
// baseline (5999.051 us; speedup 1.0000x reference)
//
#include <hip/hip_runtime.h>
#include <hip/hip_bf16.h>

// theta_solver on MI355X.
// Structure: each 256-thread block owns 64 rows. State y (fp32) lives in
// registers in MFMA C/D layout; f-inputs round-trip through LDS as bf16 in
// MFMA A-fragment layout. Weights are pre-repacked (repack_weights) into
// B-fragment order in d_ws and streamed from L2 as global_load_dwordx4.
// Per f-eval: 4 HID-chunks of 128: GEMM1(64x128,K=256) -> tanh -> LDS ->
// GEMM2 partial (K=128) accumulating F; then z = expl + h*theta*F.

typedef short short8 __attribute__((ext_vector_type(8)));
typedef float floatx4 __attribute__((ext_vector_type(4)));

#define MFMA(a, b, c) __builtin_amdgcn_mfma_f32_16x16x32_bf16((a), (b), (c), 0, 0, 0)

__device__ __forceinline__ short f2bf(float f) {
    __hip_bfloat16 h = __float2bfloat16(f);
    return *reinterpret_cast<short*>(&h);
}

__device__ __forceinline__ float fast_tanh(float x) {
    // tanh(x) = 1 - 2/(1+e^{2x}); exact identity, graceful at +/-inf.
    float e = __expf(2.0f * x);
    return 1.0f - 2.0f * __builtin_amdgcn_rcpf(1.0f + e);
}

// ---------------------------------------------------------------------------
// Weight repack: W1 [256x512] f32 -> W1p bf16 in B-frag blocks:
//   block bi = ct*8 + s   (ct = n>>4 coltile, s = kstep of 32)
//   elem: W1p[(bi*64 + lane)*8 + j] = bf16(W1[(32s + (lane>>4)*8 + j)*512 + 16ct + (lane&15)])
// W2 [512x256] f32 -> W2p, bi = ct*16 + s (s in 0..15), row stride 256.
// ---------------------------------------------------------------------------
__global__ void repack_weights(const float* __restrict__ W1,
                               const float* __restrict__ W2,
                               short* __restrict__ W1p,
                               short* __restrict__ W2p) {
    int t = blockIdx.x * blockDim.x + threadIdx.x;  // 0..32767
    int lane = t & 63;
    int q = lane >> 4, c = lane & 15;
    if (t < 16384) {
        int s = (t >> 6) & 7;
        int ct = t >> 9;  // 0..31
        short8 v;
#pragma unroll
        for (int j = 0; j < 8; ++j) {
            int k = 32 * s + 8 * q + j;
            int n = 16 * ct + c;
            v[j] = f2bf(W1[k * 512 + n]);
        }
        *reinterpret_cast<short8*>(&W1p[t * 8]) = v;
    } else {
        int t2 = t - 16384;
        int s = (t2 >> 6) & 15;
        int ct = t2 >> 10;  // 0..15
        short8 v;
#pragma unroll
        for (int j = 0; j < 8; ++j) {
            int k = 32 * s + 8 * q + j;
            int n = 16 * ct + c;
            v[j] = f2bf(W2[k * 256 + n]);
        }
        *reinterpret_cast<short8*>(&W2p[t2 * 8]) = v;
    }
}

// ---------------------------------------------------------------------------
// One f-eval: facc[mt][nt] (C-layout, wave w owns F cols [64w,64w+64)) =
//   tanh(Yb @ W1 + b1) @ W2 + b2  over the 64-row slab in Yb.
// ---------------------------------------------------------------------------
__device__ __forceinline__ void eval_f(
    const short* __restrict__ W1p, const short* __restrict__ W2p,
    const float* __restrict__ b1, const float* __restrict__ b2,
    short* __restrict__ Yb, short* __restrict__ Hc,
    int w, int lane, int q, int c,
    floatx4 (&facc)[4][4]) {
    // init F accumulators with b2 (bias depends on col = lane&15 only)
#pragma unroll
    for (int nt = 0; nt < 4; ++nt) {
        float bv = b2[64 * w + 16 * nt + c];
        floatx4 f0 = {bv, bv, bv, bv};
#pragma unroll
        for (int mt = 0; mt < 4; ++mt) facc[mt][nt] = f0;
    }

#pragma unroll 1
    for (int hc = 0; hc < 4; ++hc) {
        // ---- GEMM1 chunk: G[64 x 32] per wave (cols 128*hc + 32*w + [0,32))
        floatx4 g[4][2];
#pragma unroll
        for (int nt = 0; nt < 2; ++nt) {
            float bv = b1[128 * hc + 32 * w + 16 * nt + c];
            floatx4 g0 = {bv, bv, bv, bv};
#pragma unroll
            for (int mt = 0; mt < 4; ++mt) g[mt][nt] = g0;
        }
        const short* w1base = W1p + (8 * hc + 2 * w) * 4096 + lane * 8;
#pragma unroll
        for (int s = 0; s < 8; ++s) {
            short8 a0 = *reinterpret_cast<const short8*>(&Yb[((0 + s) * 64 + lane) * 8]);
            short8 a1 = *reinterpret_cast<const short8*>(&Yb[((8 + s) * 64 + lane) * 8]);
            short8 a2 = *reinterpret_cast<const short8*>(&Yb[((16 + s) * 64 + lane) * 8]);
            short8 a3 = *reinterpret_cast<const short8*>(&Yb[((24 + s) * 64 + lane) * 8]);
            short8 wb0 = *reinterpret_cast<const short8*>(&w1base[(0 * 8 + s) * 512]);
            short8 wb1 = *reinterpret_cast<const short8*>(&w1base[(1 * 8 + s) * 512]);
            g[0][0] = MFMA(a0, wb0, g[0][0]);
            g[1][0] = MFMA(a1, wb0, g[1][0]);
            g[2][0] = MFMA(a2, wb0, g[2][0]);
            g[3][0] = MFMA(a3, wb0, g[3][0]);
            g[0][1] = MFMA(a0, wb1, g[0][1]);
            g[1][1] = MFMA(a1, wb1, g[1][1]);
            g[2][1] = MFMA(a2, wb1, g[2][1]);
            g[3][1] = MFMA(a3, wb1, g[3][1]);
        }
        __syncthreads();  // previous chunk's GEMM2 readers of Hc are done
        // ---- tanh + transpose-scatter into Hc (A-frag layout, chunk-local k)
#pragma unroll
        for (int mt = 0; mt < 4; ++mt) {
#pragma unroll
            for (int nt = 0; nt < 2; ++nt) {
#pragma unroll
                for (int r = 0; r < 4; ++r) {
                    float t = fast_tanh(g[mt][nt][r]);
                    // chunk-local col kk = 32w + 16nt + c; block s = w
                    int lp = (4 * q + r) + 16 * ((2 * nt + (c >> 3)) & 3);
                    Hc[((mt * 4 + w) * 64 + lp) * 8 + (c & 7)] = f2bf(t);
                }
            }
        }
        __syncthreads();  // Hc chunk complete for all waves
        // ---- GEMM2 partial: F[64 x 64] per wave += Hc[64x128] @ W2chunk
        const short* w2base = W2p + (64 * w + 4 * hc) * 512 + lane * 8;
#pragma unroll
        for (int ks = 0; ks < 4; ++ks) {
            short8 a0 = *reinterpret_cast<const short8*>(&Hc[((0 + ks) * 64 + lane) * 8]);
            short8 a1 = *reinterpret_cast<const short8*>(&Hc[((4 + ks) * 64 + lane) * 8]);
            short8 a2 = *reinterpret_cast<const short8*>(&Hc[((8 + ks) * 64 + lane) * 8]);
            short8 a3 = *reinterpret_cast<const short8*>(&Hc[((12 + ks) * 64 + lane) * 8]);
            short8 wb0 = *reinterpret_cast<const short8*>(&w2base[(0 * 16 + ks) * 512]);
            short8 wb1 = *reinterpret_cast<const short8*>(&w2base[(1 * 16 + ks) * 512]);
            short8 wb2 = *reinterpret_cast<const short8*>(&w2base[(2 * 16 + ks) * 512]);
            short8 wb3 = *reinterpret_cast<const short8*>(&w2base[(3 * 16 + ks) * 512]);
#pragma unroll
            for (int mt = 0; mt < 4; ++mt) {
                short8 am = (mt == 0) ? a0 : (mt == 1) ? a1 : (mt == 2) ? a2 : a3;
                facc[mt][0] = MFMA(am, wb0, facc[mt][0]);
                facc[mt][1] = MFMA(am, wb1, facc[mt][1]);
                facc[mt][2] = MFMA(am, wb2, facc[mt][2]);
                facc[mt][3] = MFMA(am, wb3, facc[mt][3]);
            }
        }
    }
}

__global__ __launch_bounds__(256, 2) void theta_main(
    const float* __restrict__ x,
    const float* __restrict__ b1,
    const float* __restrict__ b2,
    const short* __restrict__ W1p,
    const short* __restrict__ W2p,
    float* __restrict__ out) {
    __shared__ __align__(16) short Yb[16384];  // 64 rows x 256 k, A-frag layout, 32 KB
    __shared__ __align__(16) short Hc[8192];   // 64 rows x 128 k chunk, 16 KB

    const int tid = threadIdx.x;
    const int w = tid >> 6;
    const int lane = tid & 63;
    const int q = lane >> 4, c = lane & 15;
    const int row0 = blockIdx.x << 6;
    const float HT = 0.0625f;  // h*theta == h*(1-theta)

    // y state (becomes expl during FP iters), fp32, C-layout. Wave w owns cols [64w, 64w+64).
    float yv[4][4][4];
#pragma unroll
    for (int mt = 0; mt < 4; ++mt)
#pragma unroll
        for (int nt = 0; nt < 4; ++nt)
#pragma unroll
            for (int r = 0; r < 4; ++r)
                yv[mt][nt][r] = x[(row0 + 16 * mt + 4 * q + r) * 256 + 64 * w + 16 * nt + c];

    // initial Yb = bf16(x) in A-frag layout; wave w fills m-tile w
#pragma unroll
    for (int s = 0; s < 8; ++s) {
        short8 v;
#pragma unroll
        for (int j = 0; j < 8; ++j)
            v[j] = f2bf(x[(row0 + 16 * w + c) * 256 + 32 * s + 8 * q + j]);
        *reinterpret_cast<short8*>(&Yb[((w * 8 + s) * 64 + lane) * 8]) = v;
    }
    __syncthreads();

    floatx4 facc[4][4];

#pragma unroll 1
    for (int step = 0; step < 8; ++step) {
        // ---- explicit eval: F = f(y_n)
        eval_f(W1p, W2p, b1, b2, Yb, Hc, w, lane, q, c, facc);
        // expl = y + HT*F (in place); z1 = expl + HT*F -> Yb
#pragma unroll
        for (int mt = 0; mt < 4; ++mt)
#pragma unroll
            for (int nt = 0; nt < 4; ++nt)
#pragma unroll
                for (int r = 0; r < 4; ++r) {
                    yv[mt][nt][r] += HT * facc[mt][nt][r];
                    float z = yv[mt][nt][r] + HT * facc[mt][nt][r];
                    int k = 64 * w + 16 * nt + c;
                    int s = k >> 5;
                    int lp = (4 * q + r) + 16 * ((k >> 3) & 3);
                    Yb[((mt * 8 + s) * 64 + lp) * 8 + (c & 7)] = f2bf(z);
                }
        __syncthreads();

        // ---- 18 middle fixed-point applications (z2..z19)
#pragma unroll 1
        for (int it = 0; it < 18; ++it) {
            eval_f(W1p, W2p, b1, b2, Yb, Hc, w, lane, q, c, facc);
#pragma unroll
            for (int mt = 0; mt < 4; ++mt)
#pragma unroll
                for (int nt = 0; nt < 4; ++nt)
#pragma unroll
                    for (int r = 0; r < 4; ++r) {
                        float z = yv[mt][nt][r] + HT * facc[mt][nt][r];
                        int k = 64 * w + 16 * nt + c;
                        int s = k >> 5;
                        int lp = (4 * q + r) + 16 * ((k >> 3) & 3);
                        Yb[((mt * 8 + s) * 64 + lp) * 8 + (c & 7)] = f2bf(z);
                    }
            __syncthreads();
        }

        // ---- final application: y_{n+1} = z20 = expl + HT*f(z19), kept in fp32 regs
        eval_f(W1p, W2p, b1, b2, Yb, Hc, w, lane, q, c, facc);
#pragma unroll
        for (int mt = 0; mt < 4; ++mt)
#pragma unroll
            for (int nt = 0; nt < 4; ++nt)
#pragma unroll
                for (int r = 0; r < 4; ++r) {
                    yv[mt][nt][r] += HT * facc[mt][nt][r];
                    int k = 64 * w + 16 * nt + c;
                    int s = k >> 5;
                    int lp = (4 * q + r) + 16 * ((k >> 3) & 3);
                    Yb[((mt * 8 + s) * 64 + lp) * 8 + (c & 7)] = f2bf(yv[mt][nt][r]);
                }
        __syncthreads();
    }

    // ---- write yT
#pragma unroll
    for (int mt = 0; mt < 4; ++mt)
#pragma unroll
        for (int nt = 0; nt < 4; ++nt)
#pragma unroll
            for (int r = 0; r < 4; ++r)
                out[(row0 + 16 * mt + 4 * q + r) * 256 + 64 * w + 16 * nt + c] = yv[mt][nt][r];
}

extern "C" void kernel_launch(void* const* d_in, const int* in_sizes, int n_in,
                              void* d_out, int out_size, void* d_ws, size_t ws_size,
                              hipStream_t stream) {
    const float* x = (const float*)d_in[0];
    const float* W1 = (const float*)d_in[1];
    const float* b1 = (const float*)d_in[2];
    const float* W2 = (const float*)d_in[3];
    const float* b2 = (const float*)d_in[4];
    float* out = (float*)d_out;

    short* W1p = (short*)d_ws;            // 256*512 bf16 = 256 KB
    short* W2p = W1p + 256 * 512;         // 512*256 bf16 = 256 KB

    repack_weights<<<dim3(128), dim3(256), 0, stream>>>(W1, W2, W1p, W2p);
    theta_main<<<dim3(1024), dim3(256), 0, stream>>>(x, b1, b2, W1p, W2p, out);
}